// Round 3
// baseline (149.579 us; speedup 1.0000x reference)
//
#include <hip/hip_runtime.h>
#include <hip/hip_fp16.h>
#include <math.h>

#define HW    25600
#define WID   160
#define HEI   160
#define BB    4
#define CIN   64
#define COUT  64
#define NBN   102400
#define TSTR  162     // p0 LDS tile stride in shorts: int-stride 81 == 17 mod 32
#define ZROW  640     // index of the all-zero xbT row (boundary padding)
#define NBKT  32      // stats buckets (32 x 32 floats, 128B apart)

typedef _Float16 f16x8 __attribute__((ext_vector_type(8)));
typedef float    f32x4 __attribute__((ext_vector_type(4)));

union U4 { int i[4]; f16x8 v; };
union HU { unsigned u; __half2 h; };

__device__ __forceinline__ unsigned short f2h(float f) {
    return __half_as_ushort(__float2half(f));   // RNE
}

// fast tanh: 1 - 2/(e^{2x}+1), safe at +-inf (rcp(inf)=0 -> 1)
__device__ __forceinline__ float ftanh(float x) {
    float e = __builtin_amdgcn_exp2f(x * 2.8853900817779268f);  // 2*log2(e)
    return 1.0f - 2.0f * __builtin_amdgcn_rcpf(e + 1.0f);
}

// ---------------------------------------------------------------------------
// P0: prep. blocks 0..639: transpose x[b][c][h][w] fp32 -> xbT[b][h][w][c] fp16
//     blocks 640..647: pack w_def + w_off(odd) into MFMA A-frag order (f16),
//     zero the xbT boundary row, zero the stats buckets (8-way split).
// ---------------------------------------------------------------------------
__global__ __launch_bounds__(256) void p0_prep(
        const float* __restrict__ x, const float* __restrict__ w_def,
        const float* __restrict__ w_off,
        unsigned short* __restrict__ xbT, unsigned short* __restrict__ wtA,
        unsigned short* __restrict__ wofA, float* __restrict__ stats) {
    int t = threadIdx.x;
    int blk = blockIdx.x;
    if (blk >= 640) {
        int wb = blk - 640;                        // 0..7
        // wtA: 36864 halves = 8 blocks x 18 iters x 256 threads
#pragma unroll
        for (int u = 0; u < 18; ++u) {
            int idx = t + (wb * 18 + u) * 256;
            int k = idx >> 12;
            int r = idx & 4095;
            int chalf = r >> 11;
            int og = (r >> 9) & 3;
            int L = (r >> 3) & 63;
            int j = idx & 7;
            int o = og * 16 + (L & 15);
            int c = chalf * 32 + (L >> 4) * 8 + j;
            wtA[idx] = f2h(w_def[(o * CIN + c) * 9 + k]);
        }
        if (wb < 4) {
            // wofA: 9216 halves = 4 blocks x 9 iters x 256
#pragma unroll
            for (int u = 0; u < 9; ++u) {
                int idx = t + (wb * 9 + u) * 256;
                int jj = idx & 7;
                int L  = (idx >> 3) & 63;
                int ch = (idx >> 9) & 1;
                int k  = idx >> 10;
                int j  = L & 15;
                int c  = ch * 32 + (L >> 4) * 8 + jj;
                wofA[idx] = (j < 9) ? f2h(w_off[((2 * j + 1) * CIN + c) * 9 + k])
                                    : (unsigned short)0;
            }
        } else {
            // zero boundary row: 10240 u16 = 5120 u32 = 4 blocks x 5 x 256
            unsigned* z = (unsigned*)(xbT + ZROW * (WID * 64));
#pragma unroll
            for (int u = 0; u < 5; ++u)
                z[((wb - 4) * 5 + u) * 256 + t] = 0;
        }
        if (wb == 0) {                             // 32 buckets x 32 floats
            stats[t] = 0.f; stats[256 + t] = 0.f;
            stats[512 + t] = 0.f; stats[768 + t] = 0.f;
        }
        return;
    }
    __shared__ __align__(16) unsigned short tile[CIN * TSTR];  // [c][w]
    int b = blk / HEI, h = blk % HEI;
    const float* xp = x + (b * CIN) * HW + h * WID;
    unsigned* ti = (unsigned*)tile;
#pragma unroll
    for (int u = 0; u < 10; ++u) {
        int e = t + u * 256;                       // 0..2559 = 64 c x 40 quads
        int c = e / 40, wq = e - c * 40;
        const float4 v = *(const float4*)(xp + c * HW + 4 * wq);
        unsigned p01 = f2h(v.x) | ((unsigned)f2h(v.y) << 16);
        unsigned p23 = f2h(v.z) | ((unsigned)f2h(v.w) << 16);
        ti[81 * c + 2 * wq]     = p01;
        ti[81 * c + 2 * wq + 1] = p23;
    }
    __syncthreads();
    unsigned* dst = (unsigned*)(xbT + (b * HEI + h) * (WID * 64));
#pragma unroll
    for (int u = 0; u < 20; ++u) {
        int e = t + u * 256;                       // 0..5119 = 160 w x 32 cpair
        int w = e >> 5, cp = e & 31;
        unsigned lo = tile[(2 * cp) * TSTR + w];
        unsigned hi = tile[(2 * cp + 1) * TSTR + w];
        dst[e] = lo | (hi << 16);
    }
}

// ---------------------------------------------------------------------------
// K1 v5: offset conv via f16 MFMA. 1280 half-row blocks x 320 threads.
//  - static 9-tap unroll via zero-row padding (no runtime bounds)
//  - weight frags loaded in-loop (single-use; L2 serves the broadcast)
//  - __launch_bounds__(320,4) caps VGPR <= 128 -> 16 waves/CU
//  - stats scattered into 32 buckets
// ---------------------------------------------------------------------------
__global__ __launch_bounds__(320, 4) void k1_offconv_mfma(
        const unsigned short* __restrict__ xbT,
        const unsigned short* __restrict__ wofA,
        const float* __restrict__ b_off,
        float* __restrict__ off_odd, float* __restrict__ stats) {
    int t = threadIdx.x;
    int blk = blockIdx.x;                          // 0..1279
    int xcd = blk & 7;
    int idx = blk >> 3;                            // 0..159
    int b   = idx / 40;
    int r2  = idx - b * 40;                        // 0..39
    int h   = xcd * 20 + (r2 >> 1);
    int p0  = (r2 & 1) * 80;
    int wave = t >> 6, lane = t & 63;
    int l15 = lane & 15, q = lane >> 4;
    int px  = p0 + wave * 16 + l15;

    f32x4 acc = (f32x4){0.f, 0.f, 0.f, 0.f};
#pragma unroll
    for (int k = 0; k < 9; ++k) {
        int py  = h + k - 4;
        int row = ((unsigned)py < HEI) ? (b * HEI + py) : ZROW;  // zero-pad rows
        const unsigned short* sp = xbT + row * (WID * 64) + px * 64;
        f16x8 a0 = *(const f16x8*)(wofA + ((k * 2 + 0) * 64 + lane) * 8);
        f16x8 a1 = *(const f16x8*)(wofA + ((k * 2 + 1) * 64 + lane) * 8);
        f16x8 b0 = *(const f16x8*)(sp + q * 8);
        f16x8 b1 = *(const f16x8*)(sp + 32 + q * 8);
        acc = __builtin_amdgcn_mfma_f32_16x16x32_f16(a0, b0, acc, 0, 0, 0);
        acc = __builtin_amdgcn_mfma_f32_16x16x32_f16(a1, b1, acc, 0, 0, 0);
    }

    // epilogue: bias, store, fused BN stats
    float sS[4] = {0.f, 0.f, 0.f, 0.f}, sQ[4] = {0.f, 0.f, 0.f, 0.f};
#pragma unroll
    for (int r = 0; r < 4; ++r) {
        int j = q * 4 + r;
        if (j < 9) {
            float v = acc[r] + b_off[2 * j + 1];
            off_odd[(b * 9 + j) * HW + h * WID + px] = v;
            sS[r] = v; sQ[r] = v * v;
        }
    }
#pragma unroll
    for (int o = 1; o < 16; o <<= 1) {
#pragma unroll
        for (int r = 0; r < 4; ++r) {
            sS[r] += __shfl_xor(sS[r], o);
            sQ[r] += __shfl_xor(sQ[r], o);
        }
    }
    __shared__ float redS[5][16], redQ[5][16];
    if (l15 == 0) {
#pragma unroll
        for (int r = 0; r < 4; ++r) {
            int j = q * 4 + r;
            if (j < 9) { redS[wave][j] = sS[r]; redQ[wave][j] = sQ[r]; }
        }
    }
    __syncthreads();
    if (t < 18) {
        int j = (t < 9) ? t : t - 9;
        float v = 0.f;
#pragma unroll
        for (int w = 0; w < 5; ++w)
            v += (t < 9) ? redS[w][j] : redQ[w][j];
        atomicAdd(&stats[(blk & (NBKT - 1)) * 32 + t], v);   // per-bucket
    }
}

// ---------------------------------------------------------------------------
// K4 v9: deformable conv via f16 MFMA -- REGISTER-RESIDENT samples.
//  - each wave owns one 16-px tile (wave = pxt); every lane gathers exactly
//    the 16 channels its MFMA B-frag needs (4x int4 L2 loads), lerps them
//    with packed half2 FMAs, and feeds MFMA directly from registers.
//  - NO sample LDS buffer, NO double-buffer, NO per-tap barriers (was:
//    50 b128 LDS wave-instrs + 1 barrier per block-tap).
//  - each wave computes all 4 output groups: acc[4] x f32x4; weight A-frags
//    re-read by 5 waves (same addresses chip-wide -> L1/L2 broadcast).
//  - accumulation order per output element identical to v8 (bit-exact).
// ---------------------------------------------------------------------------
__global__ __launch_bounds__(320, 4) void k4_deform_mfma(
        const unsigned short* __restrict__ xbT,
        const float* __restrict__ off_odd,
        const float* __restrict__ stats,
        const float* __restrict__ gamma,
        const float* __restrict__ beta,
        const unsigned short* __restrict__ wtA,
        const float* __restrict__ b_def,
        float* __restrict__ out) {
    __shared__ unsigned P0h[9][80], P1h[9][80];    // packed (s,s) half2
    __shared__ int      PXI[9][80];                // xi0 | xi1<<16
    __shared__ float    ssum[18];                  // bucket-summed BN stats

    int t   = threadIdx.x;
    int blk = blockIdx.x;                          // 0..1279
    int xcd = blk & 7;
    int idx = blk >> 3;                            // 0..159
    int b   = idx / 40;
    int r2  = idx - b * 40;                        // 0..39
    int h   = xcd * 20 + (r2 >> 1);
    int p0  = (r2 & 1) * 80;
    int wave = t >> 6, lane = t & 63;              // wave = pxt (0..4)
    int l15 = lane & 15, q = lane >> 4;
    int pxl = wave * 16 + l15;                     // local px 0..79

    // ---- sum the 32 stat buckets ----
    if (t < 18) {
        float v = 0.f;
#pragma unroll
        for (int xx = 0; xx < NBKT; ++xx) v += stats[xx * 32 + t];
        ssum[t] = v;
    }
    __syncthreads();

    // ---- prep: offsets -> sampling params (fused BN+tanh+convert) ----
    if (t < 160) {
        int half = (t >= 80) ? 1 : 0;
        int pp   = t - half * 80;
        int px   = p0 + pp;
        int j0   = half * 4;                       // half0: j=0..4, half1: j=4..8
        float tv[5];
#pragma unroll
        for (int u = 0; u < 5; ++u) {
            int j = j0 + u;
            float mean = ssum[j] * (1.0f / NBN);
            float var  = ssum[9 + j] * (1.0f / NBN) - mean * mean;
            float inv  = rsqrtf(var + 1e-5f);
            float v = off_odd[(b * 9 + j) * HW + h * WID + px];
            tv[u] = ftanh((v - mean) * inv * gamma[2 * j + 1] + beta[2 * j + 1]);
        }
        float dxv[5];
        if (half == 0) {                           // reverse cumsum into center
            dxv[4] = tv[4];
#pragma unroll
            for (int i = 3; i >= 0; --i) dxv[i] = dxv[i + 1] + tv[i];
        } else {                                   // forward cumsum from center
            dxv[0] = tv[0];
#pragma unroll
            for (int i = 1; i < 5; ++i) dxv[i] = dxv[i - 1] + tv[i];
        }
#pragma unroll
        for (int u = 0; u < 5; ++u) {
            int j = j0 + u;
            int py = h + j - 4;
            bool rowok = (py >= 0) && (py < HEI);
            float pxf = (float)px + dxv[u];
            float x0f = floorf(pxf);
            float fx  = pxf - x0f;
            int   x0  = (int)x0f;
            float s0f = (rowok && x0 >= 0 && x0 < WID) ? 1.f - fx : 0.f;
            float s1f = (rowok && x0 >= -1 && x0 < WID - 1) ? fx : 0.f;
            unsigned h0 = f2h(s0f), h1 = f2h(s1f);
            P0h[j][pp] = h0 | (h0 << 16);
            P1h[j][pp] = h1 | (h1 << 16);
            int xi0 = min(max(x0, 0), WID - 1);
            int xi1 = min(max(x0 + 1, 0), WID - 1);
            PXI[j][pp] = xi0 | (xi1 << 16);
        }
    }
    __syncthreads();                               // the ONLY main barrier

    f32x4 acc[4];
#pragma unroll
    for (int g = 0; g < 4; ++g) acc[g] = (f32x4){0.f, 0.f, 0.f, 0.f};

#pragma unroll 3
    for (int k = 0; k < 9; ++k) {
        int pyc = min(max(h + k - 4, 0), HEI - 1);
        const int4* rowI4 = (const int4*)(xbT + (b * HEI + pyc) * (WID * 64));
        int xi = PXI[k][pxl];
        HU s0; s0.u = P0h[k][pxl];
        HU s1; s1.u = P1h[k][pxl];
        int i0 = (xi & 0xffff) * 8 + q;            // 8 int4 per px; chunk q
        int i1 = (xi >> 16) * 8 + q;
        int4 A0 = rowI4[i0];                       // ch q*8..q*8+7   @ x0
        int4 B0 = rowI4[i1];                       //                 @ x0+1
        int4 A1 = rowI4[i0 + 4];                   // ch 32+q*8..+7   @ x0
        int4 B1 = rowI4[i1 + 4];                   //                 @ x0+1
        U4 f0, f1;
#pragma unroll
        for (int ii = 0; ii < 4; ++ii) {
            HU a, bb, r;
            a.u  = (unsigned)(&A0.x)[ii];
            bb.u = (unsigned)(&B0.x)[ii];
            r.h  = __hfma2(s1.h, bb.h, __hmul2(s0.h, a.h));
            f0.i[ii] = (int)r.u;
            a.u  = (unsigned)(&A1.x)[ii];
            bb.u = (unsigned)(&B1.x)[ii];
            r.h  = __hfma2(s1.h, bb.h, __hmul2(s0.h, a.h));
            f1.i[ii] = (int)r.u;
        }
#pragma unroll
        for (int g = 0; g < 4; ++g) {
            f16x8 w0 = *(const f16x8*)(wtA + (((k * 2 + 0) * 4 + g) * 64 + lane) * 8);
            f16x8 w1 = *(const f16x8*)(wtA + (((k * 2 + 1) * 4 + g) * 64 + lane) * 8);
            acc[g] = __builtin_amdgcn_mfma_f32_16x16x32_f16(w0, f0.v, acc[g], 0, 0, 0);
            acc[g] = __builtin_amdgcn_mfma_f32_16x16x32_f16(w1, f1.v, acc[g], 0, 0, 0);
        }
    }

    // ---- epilogue: each wave writes its 16 px for all 64 outputs ----
#pragma unroll
    for (int g = 0; g < 4; ++g) {
#pragma unroll
        for (int r = 0; r < 4; ++r) {
            int o = g * 16 + q * 4 + r;
            out[(b * COUT + o) * HW + h * WID + p0 + pxl] = acc[g][r] + b_def[o];
        }
    }
}

// ---------------------------------------------------------------------------
extern "C" void kernel_launch(void* const* d_in, const int* in_sizes, int n_in,
                              void* d_out, int out_size, void* d_ws, size_t ws_size,
                              hipStream_t stream) {
    const float* x     = (const float*)d_in[0];
    const float* w_off = (const float*)d_in[1];
    const float* b_off = (const float*)d_in[2];
    const float* gamma = (const float*)d_in[3];
    const float* beta  = (const float*)d_in[4];
    const float* w_def = (const float*)d_in[5];
    const float* b_def = (const float*)d_in[6];
    float* out = (float*)d_out;

    // workspace layout: ~17.0 MB
    float* off_odd       = (float*)d_ws;                    // 921600 f
    float* stats         = off_odd + 921600;                // 1024 f (32 buckets x 32)
    unsigned short* wtA  = (unsigned short*)(stats + 1024); // 36864 u16
    unsigned short* wofA = wtA + 36864;                     // 9216 u16
    unsigned short* xbT  = wofA + 9216;                     // 641 rows x 10240 u16

    p0_prep<<<648, 256, 0, stream>>>(x, w_def, w_off, xbT, wtA, wofA, stats);
    k1_offconv_mfma<<<1280, 320, 0, stream>>>(xbT, wofA, b_off, off_odd, stats);
    k4_deform_mfma<<<1280, 320, 0, stream>>>(xbT, off_odd, stats, gamma, beta,
                                             wtA, b_def, out);
}

// Round 4
// 140.639 us; speedup vs baseline: 1.0636x; 1.0636x over previous
//
#include <hip/hip_runtime.h>
#include <hip/hip_fp16.h>
#include <math.h>

#define HW    25600
#define WID   160
#define HEI   160
#define BB    4
#define CIN   64
#define COUT  64
#define NBN   102400
#define TSTR  162     // p0 LDS tile stride in shorts: int-stride 81 == 17 mod 32
#define ZROW  640     // index of the all-zero xbT row (boundary padding)
#define NBKT  32      // stats buckets (32 x 32 floats, 128B apart)

typedef _Float16 f16x8 __attribute__((ext_vector_type(8)));
typedef float    f32x4 __attribute__((ext_vector_type(4)));

union U4 { int i[4]; f16x8 v; };
union HU { unsigned u; __half2 h; };

__device__ __forceinline__ unsigned short f2h(float f) {
    return __half_as_ushort(__float2half(f));   // RNE
}

// fast tanh: 1 - 2/(e^{2x}+1), safe at +-inf (rcp(inf)=0 -> 1)
__device__ __forceinline__ float ftanh(float x) {
    float e = __builtin_amdgcn_exp2f(x * 2.8853900817779268f);  // 2*log2(e)
    return 1.0f - 2.0f * __builtin_amdgcn_rcpf(e + 1.0f);
}

// ---------------------------------------------------------------------------
// P0: prep. blocks 0..639: transpose x[b][c][h][w] fp32 -> xbT[b][h][w][c] fp16
//     blocks 640..647: pack w_def + w_off(odd) into MFMA A-frag order (f16),
//     zero the xbT boundary row, zero the stats buckets (8-way split).
// ---------------------------------------------------------------------------
__global__ __launch_bounds__(256) void p0_prep(
        const float* __restrict__ x, const float* __restrict__ w_def,
        const float* __restrict__ w_off,
        unsigned short* __restrict__ xbT, unsigned short* __restrict__ wtA,
        unsigned short* __restrict__ wofA, float* __restrict__ stats) {
    int t = threadIdx.x;
    int blk = blockIdx.x;
    if (blk >= 640) {
        int wb = blk - 640;                        // 0..7
        // wtA: 36864 halves = 8 blocks x 18 iters x 256 threads
#pragma unroll
        for (int u = 0; u < 18; ++u) {
            int idx = t + (wb * 18 + u) * 256;
            int k = idx >> 12;
            int r = idx & 4095;
            int chalf = r >> 11;
            int og = (r >> 9) & 3;
            int L = (r >> 3) & 63;
            int j = idx & 7;
            int o = og * 16 + (L & 15);
            int c = chalf * 32 + (L >> 4) * 8 + j;
            wtA[idx] = f2h(w_def[(o * CIN + c) * 9 + k]);
        }
        if (wb < 4) {
            // wofA: 9216 halves = 4 blocks x 9 iters x 256
#pragma unroll
            for (int u = 0; u < 9; ++u) {
                int idx = t + (wb * 9 + u) * 256;
                int jj = idx & 7;
                int L  = (idx >> 3) & 63;
                int ch = (idx >> 9) & 1;
                int k  = idx >> 10;
                int j  = L & 15;
                int c  = ch * 32 + (L >> 4) * 8 + jj;
                wofA[idx] = (j < 9) ? f2h(w_off[((2 * j + 1) * CIN + c) * 9 + k])
                                    : (unsigned short)0;
            }
        } else {
            // zero boundary row: 10240 u16 = 5120 u32 = 4 blocks x 5 x 256
            unsigned* z = (unsigned*)(xbT + ZROW * (WID * 64));
#pragma unroll
            for (int u = 0; u < 5; ++u)
                z[((wb - 4) * 5 + u) * 256 + t] = 0;
        }
        if (wb == 0) {                             // 32 buckets x 32 floats
            stats[t] = 0.f; stats[256 + t] = 0.f;
            stats[512 + t] = 0.f; stats[768 + t] = 0.f;
        }
        return;
    }
    __shared__ __align__(16) unsigned short tile[CIN * TSTR];  // [c][w]
    int b = blk / HEI, h = blk % HEI;
    const float* xp = x + (b * CIN) * HW + h * WID;
    unsigned* ti = (unsigned*)tile;
#pragma unroll
    for (int u = 0; u < 10; ++u) {
        int e = t + u * 256;                       // 0..2559 = 64 c x 40 quads
        int c = e / 40, wq = e - c * 40;
        const float4 v = *(const float4*)(xp + c * HW + 4 * wq);
        unsigned p01 = f2h(v.x) | ((unsigned)f2h(v.y) << 16);
        unsigned p23 = f2h(v.z) | ((unsigned)f2h(v.w) << 16);
        ti[81 * c + 2 * wq]     = p01;
        ti[81 * c + 2 * wq + 1] = p23;
    }
    __syncthreads();
    unsigned* dst = (unsigned*)(xbT + (b * HEI + h) * (WID * 64));
#pragma unroll
    for (int u = 0; u < 20; ++u) {
        int e = t + u * 256;                       // 0..5119 = 160 w x 32 cpair
        int w = e >> 5, cp = e & 31;
        unsigned lo = tile[(2 * cp) * TSTR + w];
        unsigned hi = tile[(2 * cp + 1) * TSTR + w];
        dst[e] = lo | (hi << 16);
    }
}

// ---------------------------------------------------------------------------
// K1 v5: offset conv via f16 MFMA. 1280 half-row blocks x 320 threads.
//  - static 9-tap unroll via zero-row padding (no runtime bounds)
//  - weight frags loaded in-loop (single-use; L2 serves the broadcast)
//  - __launch_bounds__(320,4) caps VGPR <= 128 -> 16 waves/CU
//  - stats scattered into 32 buckets
// ---------------------------------------------------------------------------
__global__ __launch_bounds__(320, 4) void k1_offconv_mfma(
        const unsigned short* __restrict__ xbT,
        const unsigned short* __restrict__ wofA,
        const float* __restrict__ b_off,
        float* __restrict__ off_odd, float* __restrict__ stats) {
    int t = threadIdx.x;
    int blk = blockIdx.x;                          // 0..1279
    int xcd = blk & 7;
    int idx = blk >> 3;                            // 0..159
    int b   = idx / 40;
    int r2  = idx - b * 40;                        // 0..39
    int h   = xcd * 20 + (r2 >> 1);
    int p0  = (r2 & 1) * 80;
    int wave = t >> 6, lane = t & 63;
    int l15 = lane & 15, q = lane >> 4;
    int px  = p0 + wave * 16 + l15;

    f32x4 acc = (f32x4){0.f, 0.f, 0.f, 0.f};
#pragma unroll
    for (int k = 0; k < 9; ++k) {
        int py  = h + k - 4;
        int row = ((unsigned)py < HEI) ? (b * HEI + py) : ZROW;  // zero-pad rows
        const unsigned short* sp = xbT + row * (WID * 64) + px * 64;
        f16x8 a0 = *(const f16x8*)(wofA + ((k * 2 + 0) * 64 + lane) * 8);
        f16x8 a1 = *(const f16x8*)(wofA + ((k * 2 + 1) * 64 + lane) * 8);
        f16x8 b0 = *(const f16x8*)(sp + q * 8);
        f16x8 b1 = *(const f16x8*)(sp + 32 + q * 8);
        acc = __builtin_amdgcn_mfma_f32_16x16x32_f16(a0, b0, acc, 0, 0, 0);
        acc = __builtin_amdgcn_mfma_f32_16x16x32_f16(a1, b1, acc, 0, 0, 0);
    }

    // epilogue: bias, store, fused BN stats
    float sS[4] = {0.f, 0.f, 0.f, 0.f}, sQ[4] = {0.f, 0.f, 0.f, 0.f};
#pragma unroll
    for (int r = 0; r < 4; ++r) {
        int j = q * 4 + r;
        if (j < 9) {
            float v = acc[r] + b_off[2 * j + 1];
            off_odd[(b * 9 + j) * HW + h * WID + px] = v;
            sS[r] = v; sQ[r] = v * v;
        }
    }
#pragma unroll
    for (int o = 1; o < 16; o <<= 1) {
#pragma unroll
        for (int r = 0; r < 4; ++r) {
            sS[r] += __shfl_xor(sS[r], o);
            sQ[r] += __shfl_xor(sQ[r], o);
        }
    }
    __shared__ float redS[5][16], redQ[5][16];
    if (l15 == 0) {
#pragma unroll
        for (int r = 0; r < 4; ++r) {
            int j = q * 4 + r;
            if (j < 9) { redS[wave][j] = sS[r]; redQ[wave][j] = sQ[r]; }
        }
    }
    __syncthreads();
    if (t < 18) {
        int j = (t < 9) ? t : t - 9;
        float v = 0.f;
#pragma unroll
        for (int w = 0; w < 5; ++w)
            v += (t < 9) ? redS[w][j] : redQ[w][j];
        atomicAdd(&stats[(blk & (NBKT - 1)) * 32 + t], v);   // per-bucket
    }
}

// ---------------------------------------------------------------------------
// K4 v10: deformable conv via f16 MFMA -- v8 build + v9 consume.
//  - build (gather+lerp) stays COOPERATIVE & COALESCED: 320 threads x 2 units,
//    each unit = (px, c4): 8 lanes cover one px's full 128B span -> same
//    perfectly-coalesced VMEM pattern as v8.  Writes S in LDS (dbuf).
//  - consume is SPLIT-BY-PX: wave = one 16-px tile; each wave reads only ITS
//    S-slice (2 ds_read_b128 per tap vs v8's 10) and computes all 4 o-groups
//    with weight frags streamed from L1-hot wtA (1KB-coalesced loads).
//    LDS traffic per block-tap: 50 -> 20 b128 wave-instrs.
//  - 1 barrier per tap (dbuf), batched register prefetch of next tap.
//  - per-output-element accumulation order identical to v8 (bit-exact).
// ---------------------------------------------------------------------------
__global__ __launch_bounds__(320, 4) void k4_deform_mfma(
        const unsigned short* __restrict__ xbT,
        const float* __restrict__ off_odd,
        const float* __restrict__ stats,
        const float* __restrict__ gamma,
        const float* __restrict__ beta,
        const unsigned short* __restrict__ wtA,
        const float* __restrict__ b_def,
        float* __restrict__ out) {
    __shared__ __align__(16) int S[2][80 * 36];    // samples, frag layout, dbuf
    __shared__ unsigned P0h[9][80], P1h[9][80];    // packed (s,s) half2
    __shared__ int      PXI[9][80];                // xi0 | xi1<<16
    __shared__ float    ssum[18];                  // bucket-summed BN stats

    int t   = threadIdx.x;
    int blk = blockIdx.x;                          // 0..1279
    int xcd = blk & 7;
    int idx = blk >> 3;                            // 0..159
    int b   = idx / 40;
    int r2  = idx - b * 40;                        // 0..39
    int h   = xcd * 20 + (r2 >> 1);
    int p0  = (r2 & 1) * 80;
    int wave = t >> 6, lane = t & 63;              // wave = pxt (0..4)
    int l15 = lane & 15, q = lane >> 4;

    // ---- sum the 32 stat buckets ----
    if (t < 18) {
        float v = 0.f;
#pragma unroll
        for (int xx = 0; xx < NBKT; ++xx) v += stats[xx * 32 + t];
        ssum[t] = v;
    }
    __syncthreads();

    // ---- prep: offsets -> sampling params (fused BN+tanh+convert) ----
    if (t < 160) {
        int half = (t >= 80) ? 1 : 0;
        int pp   = t - half * 80;
        int px   = p0 + pp;
        int j0   = half * 4;                       // half0: j=0..4, half1: j=4..8
        float tv[5];
#pragma unroll
        for (int u = 0; u < 5; ++u) {
            int j = j0 + u;
            float mean = ssum[j] * (1.0f / NBN);
            float var  = ssum[9 + j] * (1.0f / NBN) - mean * mean;
            float inv  = rsqrtf(var + 1e-5f);
            float v = off_odd[(b * 9 + j) * HW + h * WID + px];
            tv[u] = ftanh((v - mean) * inv * gamma[2 * j + 1] + beta[2 * j + 1]);
        }
        float dxv[5];
        if (half == 0) {                           // reverse cumsum into center
            dxv[4] = tv[4];
#pragma unroll
            for (int i = 3; i >= 0; --i) dxv[i] = dxv[i + 1] + tv[i];
        } else {                                   // forward cumsum from center
            dxv[0] = tv[0];
#pragma unroll
            for (int i = 1; i < 5; ++i) dxv[i] = dxv[i - 1] + tv[i];
        }
#pragma unroll
        for (int u = 0; u < 5; ++u) {
            int j = j0 + u;
            int py = h + j - 4;
            bool rowok = (py >= 0) && (py < HEI);
            float pxf = (float)px + dxv[u];
            float x0f = floorf(pxf);
            float fx  = pxf - x0f;
            int   x0  = (int)x0f;
            float s0f = (rowok && x0 >= 0 && x0 < WID) ? 1.f - fx : 0.f;
            float s1f = (rowok && x0 >= -1 && x0 < WID - 1) ? fx : 0.f;
            unsigned h0 = f2h(s0f), h1 = f2h(s1f);
            P0h[j][pp] = h0 | (h0 << 16);
            P1h[j][pp] = h1 | (h1 << 16);
            int xi0 = min(max(x0, 0), WID - 1);
            int xi1 = min(max(x0 + 1, 0), WID - 1);
            PXI[j][pp] = xi0 | (xi1 << 16);
        }
    }
    __syncthreads();

    f32x4 acc[4];
#pragma unroll
    for (int g = 0; g < 4; ++g) acc[g] = (f32x4){0.f, 0.f, 0.f, 0.f};

    // build-unit mapping: id = u*320 + t (u=0,1; exactly 640 units)
    // px = id>>3 (0..79), c4 = id&7 (int4 within 64-ch row)
    int4     A4[2], B4[2];
    unsigned sa[2], sb[2];

#define PF(kk)                                                                  \
    {                                                                           \
        int pyc = min(max(h + (kk) - 4, 0), HEI - 1);                           \
        const int4* rowI4 = (const int4*)(xbT + (b * HEI + pyc) * (WID * 64));  \
        _Pragma("unroll")                                                       \
        for (int u = 0; u < 2; ++u) {                                           \
            int id = t + u * 320;                                               \
            int pxl = id >> 3, c4 = id & 7;                                     \
            int xi = PXI[kk][pxl];                                              \
            sa[u] = P0h[kk][pxl];                                               \
            sb[u] = P1h[kk][pxl];                                               \
            A4[u] = rowI4[(xi & 0xffff) * 8 + c4];                              \
            B4[u] = rowI4[(xi >> 16) * 8 + c4];                                 \
        }                                                                       \
    }

    PF(0);
    int buf = 0;

#pragma unroll
    for (int k = 0; k < 9; ++k) {
        int* Sb = S[buf];
        // ---- build S[buf]: packed-f16 lerp of int4 spans (coalesced) ----
#pragma unroll
        for (int u = 0; u < 2; ++u) {
            int id = t + u * 320;
            int pxl = id >> 3, c4 = id & 7;
            HU sah, sbh; sah.u = sa[u]; sbh.u = sb[u];
            int4 r4;
            HU a, bb, r;
#pragma unroll
            for (int ii = 0; ii < 4; ++ii) {
                a.u  = (unsigned)(&A4[u].x)[ii];
                bb.u = (unsigned)(&B4[u].x)[ii];
                r.h  = __hfma2(sbh.h, bb.h, __hmul2(sah.h, a.h));
                (&r4.x)[ii] = (int)r.u;
            }
            *(int4*)(Sb + pxl * 36 + (c4 << 2)) = r4;
        }
        __syncthreads();                           // S[buf] ready (1 barrier/tap)

        if (k < 8) PF(k + 1);                      // prefetch overlaps consume

        // ---- consume: wave owns 16-px tile; 2 LDS reads, 4 o-groups ----
        const int* sp = &Sb[(wave * 16 + l15) * 36];
        U4 u0, u1;
        *(int4*)u0.i = *(const int4*)(sp + q * 4);
        *(int4*)u1.i = *(const int4*)(sp + 16 + q * 4);
#pragma unroll
        for (int g = 0; g < 4; ++g) {
            f16x8 w0 = *(const f16x8*)(wtA + (((k * 2 + 0) * 4 + g) * 64 + lane) * 8);
            f16x8 w1 = *(const f16x8*)(wtA + (((k * 2 + 1) * 4 + g) * 64 + lane) * 8);
            acc[g] = __builtin_amdgcn_mfma_f32_16x16x32_f16(w0, u0.v, acc[g], 0, 0, 0);
            acc[g] = __builtin_amdgcn_mfma_f32_16x16x32_f16(w1, u1.v, acc[g], 0, 0, 0);
        }
        buf ^= 1;
    }
#undef PF

    // ---- epilogue: each wave writes its 16 px for all 64 outputs ----
#pragma unroll
    for (int g = 0; g < 4; ++g) {
#pragma unroll
        for (int r = 0; r < 4; ++r) {
            int o = g * 16 + q * 4 + r;
            out[(b * COUT + o) * HW + h * WID + p0 + wave * 16 + l15] =
                acc[g][r] + b_def[o];
        }
    }
}

// ---------------------------------------------------------------------------
extern "C" void kernel_launch(void* const* d_in, const int* in_sizes, int n_in,
                              void* d_out, int out_size, void* d_ws, size_t ws_size,
                              hipStream_t stream) {
    const float* x     = (const float*)d_in[0];
    const float* w_off = (const float*)d_in[1];
    const float* b_off = (const float*)d_in[2];
    const float* gamma = (const float*)d_in[3];
    const float* beta  = (const float*)d_in[4];
    const float* w_def = (const float*)d_in[5];
    const float* b_def = (const float*)d_in[6];
    float* out = (float*)d_out;

    // workspace layout: ~17.0 MB
    float* off_odd       = (float*)d_ws;                    // 921600 f
    float* stats         = off_odd + 921600;                // 1024 f (32 buckets x 32)
    unsigned short* wtA  = (unsigned short*)(stats + 1024); // 36864 u16
    unsigned short* wofA = wtA + 36864;                     // 9216 u16
    unsigned short* xbT  = wofA + 9216;                     // 641 rows x 10240 u16

    p0_prep<<<648, 256, 0, stream>>>(x, w_def, w_off, xbT, wtA, wofA, stats);
    k1_offconv_mfma<<<1280, 320, 0, stream>>>(xbT, wofA, b_off, off_odd, stats);
    k4_deform_mfma<<<1280, 320, 0, stream>>>(xbT, off_odd, stats, gamma, beta,
                                             wtA, b_def, out);
}

// Round 5
// 127.474 us; speedup vs baseline: 1.1734x; 1.1033x over previous
//
#include <hip/hip_runtime.h>
#include <hip/hip_fp16.h>
#include <math.h>

#define HW    25600
#define WID   160
#define HEI   160
#define BB    4
#define CIN   64
#define COUT  64
#define NBN   102400
#define TSTR  162     // p0 LDS tile stride in shorts: int-stride 81 == 17 mod 32
#define ZROW  640     // index of the all-zero xbT row (boundary padding)
#define NBKT  32      // stats buckets (32 x 32 floats, 128B apart)

typedef _Float16 f16x8 __attribute__((ext_vector_type(8)));
typedef float    f32x4 __attribute__((ext_vector_type(4)));

union U4 { int i[4]; f16x8 v; };
union HU { unsigned u; __half2 h; };

__device__ __forceinline__ unsigned short f2h(float f) {
    return __half_as_ushort(__float2half(f));   // RNE
}

// fast tanh: 1 - 2/(e^{2x}+1), safe at +-inf (rcp(inf)=0 -> 1)
__device__ __forceinline__ float ftanh(float x) {
    float e = __builtin_amdgcn_exp2f(x * 2.8853900817779268f);  // 2*log2(e)
    return 1.0f - 2.0f * __builtin_amdgcn_rcpf(e + 1.0f);
}

// ---------------------------------------------------------------------------
// P0: prep. blocks 0..639: transpose x[b][c][h][w] fp32 -> xbT[b][h][w][c] fp16
//     blocks 640..647: pack w_def + w_off(odd) into MFMA A-frag order (f16),
//     zero the xbT boundary row, zero the stats buckets (8-way split).
//     Store path widened to int4 (1KB/wave-instr, was 256B).
// ---------------------------------------------------------------------------
__global__ __launch_bounds__(256) void p0_prep(
        const float* __restrict__ x, const float* __restrict__ w_def,
        const float* __restrict__ w_off,
        unsigned short* __restrict__ xbT, unsigned short* __restrict__ wtA,
        unsigned short* __restrict__ wofA, float* __restrict__ stats) {
    int t = threadIdx.x;
    int blk = blockIdx.x;
    if (blk >= 640) {
        int wb = blk - 640;                        // 0..7
        // wtA: 36864 halves = 8 blocks x 18 iters x 256 threads
#pragma unroll
        for (int u = 0; u < 18; ++u) {
            int idx = t + (wb * 18 + u) * 256;
            int k = idx >> 12;
            int r = idx & 4095;
            int chalf = r >> 11;
            int og = (r >> 9) & 3;
            int L = (r >> 3) & 63;
            int j = idx & 7;
            int o = og * 16 + (L & 15);
            int c = chalf * 32 + (L >> 4) * 8 + j;
            wtA[idx] = f2h(w_def[(o * CIN + c) * 9 + k]);
        }
        if (wb < 4) {
            // wofA: 9216 halves = 4 blocks x 9 iters x 256
#pragma unroll
            for (int u = 0; u < 9; ++u) {
                int idx = t + (wb * 9 + u) * 256;
                int jj = idx & 7;
                int L  = (idx >> 3) & 63;
                int ch = (idx >> 9) & 1;
                int k  = idx >> 10;
                int j  = L & 15;
                int c  = ch * 32 + (L >> 4) * 8 + jj;
                wofA[idx] = (j < 9) ? f2h(w_off[((2 * j + 1) * CIN + c) * 9 + k])
                                    : (unsigned short)0;
            }
        } else {
            // zero boundary row: 10240 u16 = 5120 u32 = 4 blocks x 5 x 256
            unsigned* z = (unsigned*)(xbT + ZROW * (WID * 64));
#pragma unroll
            for (int u = 0; u < 5; ++u)
                z[((wb - 4) * 5 + u) * 256 + t] = 0;
        }
        if (wb == 0) {                             // 32 buckets x 32 floats
            stats[t] = 0.f; stats[256 + t] = 0.f;
            stats[512 + t] = 0.f; stats[768 + t] = 0.f;
        }
        return;
    }
    __shared__ __align__(16) unsigned short tile[CIN * TSTR];  // [c][w]
    int b = blk / HEI, h = blk % HEI;
    const float* xp = x + (b * CIN) * HW + h * WID;
    unsigned* ti = (unsigned*)tile;
#pragma unroll
    for (int u = 0; u < 10; ++u) {
        int e = t + u * 256;                       // 0..2559 = 64 c x 40 quads
        int c = e / 40, wq = e - c * 40;
        const float4 v = *(const float4*)(xp + c * HW + 4 * wq);
        unsigned p01 = f2h(v.x) | ((unsigned)f2h(v.y) << 16);
        unsigned p23 = f2h(v.z) | ((unsigned)f2h(v.w) << 16);
        ti[81 * c + 2 * wq]     = p01;
        ti[81 * c + 2 * wq + 1] = p23;
    }
    __syncthreads();
    unsigned* dst = (unsigned*)(xbT + (b * HEI + h) * (WID * 64));
#pragma unroll
    for (int u = 0; u < 5; ++u) {
        int e = t + u * 256;                       // 0..1279 = 160 w x 8 cquads
        int w = e >> 3, c4 = e & 7;                // c4 = group of 4 ch-pairs
        int4 vv;
#pragma unroll
        for (int ii = 0; ii < 4; ++ii) {
            int cp = c4 * 4 + ii;
            unsigned lo = tile[(2 * cp) * TSTR + w];
            unsigned hi = tile[(2 * cp + 1) * TSTR + w];
            (&vv.x)[ii] = (int)(lo | (hi << 16));
        }
        *(int4*)(dst + e * 4) = vv;                // dst[w*32 + cp] layout kept
    }
}

// ---------------------------------------------------------------------------
// K1 v5: offset conv via f16 MFMA. 1280 half-row blocks x 320 threads.
//  - static 9-tap unroll via zero-row padding (no runtime bounds)
//  - weight frags loaded in-loop (single-use; L2 serves the broadcast)
//  - __launch_bounds__(320,4) caps VGPR <= 128 -> 16 waves/CU
//  - stats scattered into 32 buckets
// ---------------------------------------------------------------------------
__global__ __launch_bounds__(320, 4) void k1_offconv_mfma(
        const unsigned short* __restrict__ xbT,
        const unsigned short* __restrict__ wofA,
        const float* __restrict__ b_off,
        float* __restrict__ off_odd, float* __restrict__ stats) {
    int t = threadIdx.x;
    int blk = blockIdx.x;                          // 0..1279
    int xcd = blk & 7;
    int idx = blk >> 3;                            // 0..159
    int b   = idx / 40;
    int r2  = idx - b * 40;                        // 0..39
    int h   = xcd * 20 + (r2 >> 1);
    int p0  = (r2 & 1) * 80;
    int wave = t >> 6, lane = t & 63;
    int l15 = lane & 15, q = lane >> 4;
    int px  = p0 + wave * 16 + l15;

    f32x4 acc = (f32x4){0.f, 0.f, 0.f, 0.f};
#pragma unroll
    for (int k = 0; k < 9; ++k) {
        int py  = h + k - 4;
        int row = ((unsigned)py < HEI) ? (b * HEI + py) : ZROW;  // zero-pad rows
        const unsigned short* sp = xbT + row * (WID * 64) + px * 64;
        f16x8 a0 = *(const f16x8*)(wofA + ((k * 2 + 0) * 64 + lane) * 8);
        f16x8 a1 = *(const f16x8*)(wofA + ((k * 2 + 1) * 64 + lane) * 8);
        f16x8 b0 = *(const f16x8*)(sp + q * 8);
        f16x8 b1 = *(const f16x8*)(sp + 32 + q * 8);
        acc = __builtin_amdgcn_mfma_f32_16x16x32_f16(a0, b0, acc, 0, 0, 0);
        acc = __builtin_amdgcn_mfma_f32_16x16x32_f16(a1, b1, acc, 0, 0, 0);
    }

    // epilogue: bias, store, fused BN stats
    float sS[4] = {0.f, 0.f, 0.f, 0.f}, sQ[4] = {0.f, 0.f, 0.f, 0.f};
#pragma unroll
    for (int r = 0; r < 4; ++r) {
        int j = q * 4 + r;
        if (j < 9) {
            float v = acc[r] + b_off[2 * j + 1];
            off_odd[(b * 9 + j) * HW + h * WID + px] = v;
            sS[r] = v; sQ[r] = v * v;
        }
    }
#pragma unroll
    for (int o = 1; o < 16; o <<= 1) {
#pragma unroll
        for (int r = 0; r < 4; ++r) {
            sS[r] += __shfl_xor(sS[r], o);
            sQ[r] += __shfl_xor(sQ[r], o);
        }
    }
    __shared__ float redS[5][16], redQ[5][16];
    if (l15 == 0) {
#pragma unroll
        for (int r = 0; r < 4; ++r) {
            int j = q * 4 + r;
            if (j < 9) { redS[wave][j] = sS[r]; redQ[wave][j] = sQ[r]; }
        }
    }
    __syncthreads();
    if (t < 18) {
        int j = (t < 9) ? t : t - 9;
        float v = 0.f;
#pragma unroll
        for (int w = 0; w < 5; ++w)
            v += (t < 9) ? redS[w][j] : redQ[w][j];
        atomicAdd(&stats[(blk & (NBKT - 1)) * 32 + t], v);   // per-bucket
    }
}

// ---------------------------------------------------------------------------
// K4 v8 (proven best): deformable conv via f16 MFMA.
//  - cooperative coalesced build (gather+lerp) -> S in LDS (frag layout, dbuf)
//  - consume: wave = o-group, weights prefetched (zero redundancy on VMEM),
//    samples read 4x from LDS (balanced vs L1-port cost of all alternatives)
//  - 1 barrier/tap; batched register prefetch of next tap's gather.
// ---------------------------------------------------------------------------
__global__ __launch_bounds__(256, 5) void k4_deform_mfma(
        const unsigned short* __restrict__ xbT,
        const float* __restrict__ off_odd,
        const float* __restrict__ stats,
        const float* __restrict__ gamma,
        const float* __restrict__ beta,
        const unsigned short* __restrict__ wtA,
        const float* __restrict__ b_def,
        float* __restrict__ out) {
    __shared__ __align__(16) int S[2][80 * 36];    // samples, frag layout, dbuf
    __shared__ unsigned P0h[9][80], P1h[9][80];    // packed (s,s) half2
    __shared__ int      PXI[9][80];                // xi0 | xi1<<16
    __shared__ float    ssum[18];                  // bucket-summed BN stats

    int t   = threadIdx.x;
    int blk = blockIdx.x;                          // 0..1279
    int xcd = blk & 7;
    int idx = blk >> 3;                            // 0..159
    int b   = idx / 40;
    int r2  = idx - b * 40;                        // 0..39
    int h   = xcd * 20 + (r2 >> 1);
    int p0  = (r2 & 1) * 80;
    int wave = t >> 6, lane = t & 63;
    int l15 = lane & 15, q = lane >> 4;

    // ---- sum the 32 stat buckets ----
    if (t < 18) {
        float v = 0.f;
#pragma unroll
        for (int xx = 0; xx < NBKT; ++xx) v += stats[xx * 32 + t];
        ssum[t] = v;
    }
    __syncthreads();

    // ---- prep: offsets -> sampling params (fused BN+tanh+convert) ----
    if (t < 160) {
        int half = (t >= 80) ? 1 : 0;
        int pp   = t - half * 80;
        int px   = p0 + pp;
        int j0   = half * 4;                       // half0: j=0..4, half1: j=4..8
        float tv[5];
#pragma unroll
        for (int u = 0; u < 5; ++u) {
            int j = j0 + u;
            float mean = ssum[j] * (1.0f / NBN);
            float var  = ssum[9 + j] * (1.0f / NBN) - mean * mean;
            float inv  = rsqrtf(var + 1e-5f);
            float v = off_odd[(b * 9 + j) * HW + h * WID + px];
            tv[u] = ftanh((v - mean) * inv * gamma[2 * j + 1] + beta[2 * j + 1]);
        }
        float dxv[5];
        if (half == 0) {                           // reverse cumsum into center
            dxv[4] = tv[4];
#pragma unroll
            for (int i = 3; i >= 0; --i) dxv[i] = dxv[i + 1] + tv[i];
        } else {                                   // forward cumsum from center
            dxv[0] = tv[0];
#pragma unroll
            for (int i = 1; i < 5; ++i) dxv[i] = dxv[i - 1] + tv[i];
        }
#pragma unroll
        for (int u = 0; u < 5; ++u) {
            int j = j0 + u;
            int py = h + j - 4;
            bool rowok = (py >= 0) && (py < HEI);
            float pxf = (float)px + dxv[u];
            float x0f = floorf(pxf);
            float fx  = pxf - x0f;
            int   x0  = (int)x0f;
            float s0f = (rowok && x0 >= 0 && x0 < WID) ? 1.f - fx : 0.f;
            float s1f = (rowok && x0 >= -1 && x0 < WID - 1) ? fx : 0.f;
            unsigned h0 = f2h(s0f), h1 = f2h(s1f);
            P0h[j][pp] = h0 | (h0 << 16);
            P1h[j][pp] = h1 | (h1 << 16);
            int xi0 = min(max(x0, 0), WID - 1);
            int xi1 = min(max(x0 + 1, 0), WID - 1);
            PXI[j][pp] = xi0 | (xi1 << 16);
        }
    }
    __syncthreads();

    f32x4 acc[5];
#pragma unroll
    for (int i = 0; i < 5; ++i) acc[i] = (f32x4){0.f, 0.f, 0.f, 0.f};

    // build-unit mapping: idx = u*256 + t (u=0,1 full, u=2 for t<128)
    // px = idx>>3 (0..79), c4 = idx&7 (int4 within 64-ch row)
    int4     A4[3], B4[3];
    unsigned sa[3], sb[3];
    f16x8    wpa, wpb;

#define PF(kk)                                                                  \
    {                                                                           \
        int pyc = min(max(h + (kk) - 4, 0), HEI - 1);                           \
        const int4* rowI4 = (const int4*)(xbT + (b * HEI + pyc) * (WID * 64));  \
        _Pragma("unroll")                                                       \
        for (int u = 0; u < 3; ++u) {                                           \
            if (u < 2 || t < 128) {                                             \
                int id = t + u * 256;                                           \
                int pxl = id >> 3, c4 = id & 7;                                 \
                int xi = PXI[kk][pxl];                                          \
                sa[u] = P0h[kk][pxl];                                           \
                sb[u] = P1h[kk][pxl];                                           \
                A4[u] = rowI4[(xi & 0xffff) * 8 + c4];                          \
                B4[u] = rowI4[(xi >> 16) * 8 + c4];                             \
            }                                                                   \
        }                                                                       \
        wpa = *(const f16x8*)(wtA + ((((kk) * 2 + 0) * 4 + wave) * 64 + lane) * 8); \
        wpb = *(const f16x8*)(wtA + ((((kk) * 2 + 1) * 4 + wave) * 64 + lane) * 8); \
    }

    PF(0);
    int buf = 0;

    for (int k = 0; k < 9; ++k) {
        int* Sb = S[buf];
        // ---- build S[buf]: packed-f16 lerp of int4 spans ----
#pragma unroll
        for (int u = 0; u < 3; ++u) {
            if (u < 2 || t < 128) {
                int id = t + u * 256;
                int pxl = id >> 3, c4 = id & 7;
                HU sah, sbh; sah.u = sa[u]; sbh.u = sb[u];
                int4 r4;
                HU a, bb, r;
#pragma unroll
                for (int ii = 0; ii < 4; ++ii) {
                    a.u  = (unsigned)(&A4[u].x)[ii];
                    bb.u = (unsigned)(&B4[u].x)[ii];
                    r.h  = __hfma2(sbh.h, bb.h, __hmul2(sah.h, a.h));
                    (&r4.x)[ii] = (int)r.u;
                }
                *(int4*)(Sb + pxl * 36 + (c4 << 2)) = r4;
            }
        }
        __syncthreads();                           // S[buf] ready (1 barrier/tap)

        f16x8 wf0 = wpa, wf1 = wpb;
        if (k < 8) PF(k + 1);                      // prefetch overlaps consume

        // ---- consume: 5 pxt x 2 ch MFMAs per wave ----
#pragma unroll
        for (int pxt = 0; pxt < 5; ++pxt) {
            const int* sp = &Sb[(pxt * 16 + l15) * 36];
            U4 u0, u1;
            *(int4*)u0.i = *(const int4*)(sp + q * 4);
            *(int4*)u1.i = *(const int4*)(sp + 16 + q * 4);
            acc[pxt] = __builtin_amdgcn_mfma_f32_16x16x32_f16(wf0, u0.v, acc[pxt], 0, 0, 0);
            acc[pxt] = __builtin_amdgcn_mfma_f32_16x16x32_f16(wf1, u1.v, acc[pxt], 0, 0, 0);
        }
        buf ^= 1;
    }
#undef PF

    // ---- epilogue ----
    float bd[4];
#pragma unroll
    for (int r = 0; r < 4; ++r) bd[r] = b_def[wave * 16 + q * 4 + r];
#pragma unroll
    for (int pxt = 0; pxt < 5; ++pxt) {
#pragma unroll
        for (int r = 0; r < 4; ++r) {
            int o = wave * 16 + q * 4 + r;
            out[(b * COUT + o) * HW + h * WID + p0 + pxt * 16 + l15] = acc[pxt][r] + bd[r];
        }
    }
}

// ---------------------------------------------------------------------------
extern "C" void kernel_launch(void* const* d_in, const int* in_sizes, int n_in,
                              void* d_out, int out_size, void* d_ws, size_t ws_size,
                              hipStream_t stream) {
    const float* x     = (const float*)d_in[0];
    const float* w_off = (const float*)d_in[1];
    const float* b_off = (const float*)d_in[2];
    const float* gamma = (const float*)d_in[3];
    const float* beta  = (const float*)d_in[4];
    const float* w_def = (const float*)d_in[5];
    const float* b_def = (const float*)d_in[6];
    float* out = (float*)d_out;

    // workspace layout: ~17.0 MB
    float* off_odd       = (float*)d_ws;                    // 921600 f
    float* stats         = off_odd + 921600;                // 1024 f (32 buckets x 32)
    unsigned short* wtA  = (unsigned short*)(stats + 1024); // 36864 u16
    unsigned short* wofA = wtA + 36864;                     // 9216 u16
    unsigned short* xbT  = wofA + 9216;                     // 641 rows x 10240 u16

    p0_prep<<<648, 256, 0, stream>>>(x, w_def, w_off, xbT, wtA, wofA, stats);
    k1_offconv_mfma<<<1280, 320, 0, stream>>>(xbT, wofA, b_off, off_odd, stats);
    k4_deform_mfma<<<1280, 256, 0, stream>>>(xbT, off_odd, stats, gamma, beta,
                                             wtA, b_def, out);
}